// Round 1
// baseline (1732.411 us; speedup 1.0000x reference)
//
#include <hip/hip_runtime.h>
#include <math.h>

#define TA 32

// ---------------------------------------------------------------------------
// Kernel 1: per-atom MLP chain + fused molecule pooling (sorted segment ids)
//   feat_emb = relu(af @ Wf + bf)            [N,128]  K=39
//   h        = relu([feat_emb,am] @ W1 + b1) [N,128]  K=384
//   out      = tanh(h @ W2 + b2)             [N,128]  K=128
//   pool: atomic sum / max / count per molecule (run-combined within tile)
// ---------------------------------------------------------------------------
__global__ __launch_bounds__(256, 2) void atom_pool_kernel(
    const float* __restrict__ af, const float* __restrict__ am,
    const float* __restrict__ Wf, const float* __restrict__ bf,
    const float* __restrict__ W1, const float* __restrict__ b1,
    const float* __restrict__ W2, const float* __restrict__ b2,
    const int* __restrict__ seg,
    float* __restrict__ sums, unsigned int* __restrict__ maxs,
    int* __restrict__ counts, int N)
{
    __shared__ float sh_feat[TA][40];
    __shared__ float sh_msg[TA][256];
    __shared__ float sh_emb[TA][128];   // feat_emb, later reused for atom_output
    __shared__ float sh_h[TA][128];
    __shared__ int   sh_seg[TA];

    const int t = threadIdx.x;
    const int base = blockIdx.x * TA;

    if (t < TA) {
        int g = base + t;
        sh_seg[t] = (g < N) ? seg[g] : -1;
    }
    for (int i = t; i < TA * 39; i += 256) {
        int a = i / 39, k = i - a * 39;
        int g = base + a;
        sh_feat[a][k] = (g < N) ? af[(size_t)g * 39 + k] : 0.0f;
    }
    for (int i = t; i < TA * 256; i += 256) {
        int a = i >> 8, k = i & 255;
        int g = base + a;
        sh_msg[a][k] = (g < N) ? am[((size_t)g << 8) + k] : 0.0f;
    }
    __syncthreads();

    const int ty = t >> 5;      // 0..7  -> atom group (4 atoms)
    const int tx = t & 31;      // 0..31 -> channel group (4 channels)
    const int a0 = ty * 4;

    // ---- phase 1: feat_emb, K = 39 ----
    {
        float acc[4][4] = {};
        const float4* Wf4 = (const float4*)Wf;
        for (int k = 0; k < 39; ++k) {
            float4 w = Wf4[k * 32 + tx];
            #pragma unroll
            for (int i = 0; i < 4; ++i) {
                float x = sh_feat[a0 + i][k];
                acc[i][0] += x * w.x; acc[i][1] += x * w.y;
                acc[i][2] += x * w.z; acc[i][3] += x * w.w;
            }
        }
        #pragma unroll
        for (int i = 0; i < 4; ++i) {
            #pragma unroll
            for (int j = 0; j < 4; ++j) {
                float v = acc[i][j] + bf[tx * 4 + j];
                sh_emb[a0 + i][tx * 4 + j] = fmaxf(v, 0.0f);
            }
        }
    }
    __syncthreads();

    // ---- phase 2: h = relu([emb(128), msg(256)] @ W1 + b1), K = 384 ----
    {
        float acc[4][4] = {};
        const float4* W14 = (const float4*)W1;
        for (int k = 0; k < 128; ++k) {
            float4 w = W14[k * 32 + tx];
            #pragma unroll
            for (int i = 0; i < 4; ++i) {
                float x = sh_emb[a0 + i][k];
                acc[i][0] += x * w.x; acc[i][1] += x * w.y;
                acc[i][2] += x * w.z; acc[i][3] += x * w.w;
            }
        }
        for (int k = 0; k < 256; ++k) {
            float4 w = W14[(k + 128) * 32 + tx];
            #pragma unroll
            for (int i = 0; i < 4; ++i) {
                float x = sh_msg[a0 + i][k];
                acc[i][0] += x * w.x; acc[i][1] += x * w.y;
                acc[i][2] += x * w.z; acc[i][3] += x * w.w;
            }
        }
        #pragma unroll
        for (int i = 0; i < 4; ++i) {
            #pragma unroll
            for (int j = 0; j < 4; ++j) {
                float v = acc[i][j] + b1[tx * 4 + j];
                sh_h[a0 + i][tx * 4 + j] = fmaxf(v, 0.0f);
            }
        }
    }
    __syncthreads();

    // ---- phase 3: atom_output = tanh(h @ W2 + b2), K = 128 ----
    {
        float acc[4][4] = {};
        const float4* W24 = (const float4*)W2;
        for (int k = 0; k < 128; ++k) {
            float4 w = W24[k * 32 + tx];
            #pragma unroll
            for (int i = 0; i < 4; ++i) {
                float x = sh_h[a0 + i][k];
                acc[i][0] += x * w.x; acc[i][1] += x * w.y;
                acc[i][2] += x * w.z; acc[i][3] += x * w.w;
            }
        }
        __syncthreads();   // everyone done reading sh_emb (phase-2 inputs long gone)
        #pragma unroll
        for (int i = 0; i < 4; ++i) {
            #pragma unroll
            for (int j = 0; j < 4; ++j) {
                sh_emb[a0 + i][tx * 4 + j] = tanhf(acc[i][j] + b2[tx * 4 + j]);
            }
        }
    }
    __syncthreads();

    // ---- phase 4: molecule pooling (segment ids sorted -> run combine) ----
    if (t < 128) {
        const int c = t;
        int cur = -1, runlen = 0;
        float rs = 0.0f, rm = -2.0f;
        for (int a = 0; a < TA; ++a) {
            int g = base + a;
            if (g >= N) break;
            int m = sh_seg[a];
            float v = sh_emb[a][c];
            if (m != cur) {
                if (cur >= 0) {
                    atomicAdd(&sums[(size_t)cur * 128 + c], rs);
                    atomicMax(&maxs[(size_t)cur * 128 + c], __float_as_uint(rm + 2.0f));
                    if (c == 0) atomicAdd(&counts[cur], runlen);
                }
                cur = m; rs = v; rm = v; runlen = 1;
            } else {
                rs += v; rm = fmaxf(rm, v); ++runlen;
            }
        }
        if (cur >= 0) {
            atomicAdd(&sums[(size_t)cur * 128 + c], rs);
            atomicMax(&maxs[(size_t)cur * 128 + c], __float_as_uint(rm + 2.0f));
            if (c == 0) atomicAdd(&counts[cur], runlen);
        }
    }
}

// ---------------------------------------------------------------------------
// Kernel 2: leaf_atom_emb = tanh(amf[leaf_idx] @ W_leaf + b_leaf)  [NL,256]
// ---------------------------------------------------------------------------
__global__ __launch_bounds__(256, 4) void leaf_kernel(
    const float* __restrict__ af, const float* __restrict__ am,
    const float* __restrict__ W, const float* __restrict__ b,
    const int* __restrict__ idx, float* __restrict__ out, int NL)
{
    __shared__ float sh_x[TA][296];
    __shared__ int sh_i[TA];
    const int t = threadIdx.x;
    const int base = blockIdx.x * TA;

    if (t < TA) {
        int r = base + t;
        sh_i[t] = (r < NL) ? idx[r] : 0;
    }
    __syncthreads();
    for (int i = t; i < TA * 295; i += 256) {
        int r = i / 295, k = i - r * 295;
        int g = sh_i[r];
        sh_x[r][k] = (k < 39) ? af[(size_t)g * 39 + k]
                              : am[((size_t)g << 8) + (k - 39)];
    }
    __syncthreads();

    const int ty = t >> 5, tx = t & 31;
    float acc[4][8] = {};
    const float4* W4 = (const float4*)W;
    for (int k = 0; k < 295; ++k) {
        float4 w0 = W4[k * 64 + tx * 2];
        float4 w1 = W4[k * 64 + tx * 2 + 1];
        #pragma unroll
        for (int i = 0; i < 4; ++i) {
            float x = sh_x[ty * 4 + i][k];
            acc[i][0] += x * w0.x; acc[i][1] += x * w0.y;
            acc[i][2] += x * w0.z; acc[i][3] += x * w0.w;
            acc[i][4] += x * w1.x; acc[i][5] += x * w1.y;
            acc[i][6] += x * w1.z; acc[i][7] += x * w1.w;
        }
    }
    #pragma unroll
    for (int i = 0; i < 4; ++i) {
        int r = base + ty * 4 + i;
        if (r >= NL) continue;
        float4 o0, o1;
        o0.x = tanhf(acc[i][0] + b[tx * 8 + 0]);
        o0.y = tanhf(acc[i][1] + b[tx * 8 + 1]);
        o0.z = tanhf(acc[i][2] + b[tx * 8 + 2]);
        o0.w = tanhf(acc[i][3] + b[tx * 8 + 3]);
        o1.x = tanhf(acc[i][4] + b[tx * 8 + 4]);
        o1.y = tanhf(acc[i][5] + b[tx * 8 + 5]);
        o1.z = tanhf(acc[i][6] + b[tx * 8 + 6]);
        o1.w = tanhf(acc[i][7] + b[tx * 8 + 7]);
        float4* o = (float4*)&out[(size_t)r * 256 + tx * 8];
        o[0] = o0; o[1] = o1;
    }
}

// ---------------------------------------------------------------------------
// Kernel 3: ring rows = tanh(amf[ring_idx] @ W_ring + b_ring), segment-summed
//           (only the gathered 120k rows are computed, not all 300k atoms)
// ---------------------------------------------------------------------------
__global__ __launch_bounds__(256, 4) void ring_kernel(
    const float* __restrict__ af, const float* __restrict__ am,
    const float* __restrict__ W, const float* __restrict__ b,
    const int* __restrict__ idx, const int* __restrict__ rseg,
    float* __restrict__ out, int NRE)
{
    __shared__ float sh_x[TA][296];
    __shared__ int sh_i[TA];
    __shared__ int sh_s[TA];
    const int t = threadIdx.x;
    const int base = blockIdx.x * TA;

    if (t < TA) {
        int r = base + t;
        sh_i[t] = (r < NRE) ? idx[r] : 0;
        sh_s[t] = (r < NRE) ? rseg[r] : -1;
    }
    __syncthreads();
    for (int i = t; i < TA * 295; i += 256) {
        int r = i / 295, k = i - r * 295;
        int g = sh_i[r];
        sh_x[r][k] = (k < 39) ? af[(size_t)g * 39 + k]
                              : am[((size_t)g << 8) + (k - 39)];
    }
    __syncthreads();

    const int ty = t >> 5, tx = t & 31;
    float acc[4][8] = {};
    const float4* W4 = (const float4*)W;
    for (int k = 0; k < 295; ++k) {
        float4 w0 = W4[k * 64 + tx * 2];
        float4 w1 = W4[k * 64 + tx * 2 + 1];
        #pragma unroll
        for (int i = 0; i < 4; ++i) {
            float x = sh_x[ty * 4 + i][k];
            acc[i][0] += x * w0.x; acc[i][1] += x * w0.y;
            acc[i][2] += x * w0.z; acc[i][3] += x * w0.w;
            acc[i][4] += x * w1.x; acc[i][5] += x * w1.y;
            acc[i][6] += x * w1.z; acc[i][7] += x * w1.w;
        }
    }
    // tanh + combine consecutive same-segment rows, then atomicAdd
    #pragma unroll
    for (int j = 0; j < 8; ++j) {
        int c = tx * 8 + j;
        float bias = b[c];
        int cur = -1; float accv = 0.0f;
        #pragma unroll
        for (int i = 0; i < 4; ++i) {
            int r = base + ty * 4 + i;
            if (r >= NRE) break;
            int s = sh_s[ty * 4 + i];
            float v = tanhf(acc[i][j] + bias);
            if (s == cur) accv += v;
            else {
                if (cur >= 0) atomicAdd(&out[(size_t)cur * 256 + c], accv);
                cur = s; accv = v;
            }
        }
        if (cur >= 0) atomicAdd(&out[(size_t)cur * 256 + c], accv);
    }
}

// ---------------------------------------------------------------------------
// Kernel 4: finalize molecule embedding (avg | max)
// ---------------------------------------------------------------------------
__global__ void finalize_kernel(const float* __restrict__ sums,
                                const unsigned int* __restrict__ maxs,
                                const int* __restrict__ counts,
                                float* __restrict__ out, int M)
{
    int tid = blockIdx.x * blockDim.x + threadIdx.x;
    if (tid >= M * 128) return;
    int m = tid >> 7, c = tid & 127;
    int cnt = counts[m];
    float denom = (float)(cnt > 0 ? cnt : 1);
    float avg = sums[tid] / denom;
    float mx = (cnt > 0) ? (__uint_as_float(maxs[tid]) - 2.0f) : 0.0f;
    out[(size_t)m * 256 + c] = avg;
    out[(size_t)m * 256 + 128 + c] = mx;
}

extern "C" void kernel_launch(void* const* d_in, const int* in_sizes, int n_in,
                              void* d_out, int out_size, void* d_ws, size_t ws_size,
                              hipStream_t stream) {
    const float* af = (const float*)d_in[0];
    const float* am = (const float*)d_in[1];
    const float* Wf = (const float*)d_in[2];
    const float* bf = (const float*)d_in[3];
    const float* W1 = (const float*)d_in[4];
    const float* b1 = (const float*)d_in[5];
    const float* W2 = (const float*)d_in[6];
    const float* b2 = (const float*)d_in[7];
    const float* WL = (const float*)d_in[8];
    const float* bL = (const float*)d_in[9];
    const float* WR = (const float*)d_in[10];
    const float* bR = (const float*)d_in[11];
    const int* seg      = (const int*)d_in[12];
    const int* leaf_idx = (const int*)d_in[13];
    const int* ring_idx = (const int*)d_in[14];
    const int* ring_seg = (const int*)d_in[15];

    const int N   = in_sizes[0] / 39;   // 300000
    const int NL  = in_sizes[13];       // 50000
    const int NRE = in_sizes[14];       // 120000
    const int M   = 10000;              // n_mols  (setup constant)
    const int NR  = 20000;              // n_rings (setup constant)

    float* out = (float*)d_out;
    float* out_mol  = out;
    float* out_leaf = out + (size_t)M * 256;
    float* out_ring = out + (size_t)M * 256 + (size_t)NL * 256;

    float*        sums   = (float*)d_ws;                 // M*128
    unsigned int* maxs   = (unsigned int*)(sums + (size_t)M * 128);
    int*          counts = (int*)(maxs + (size_t)M * 128);

    hipMemsetAsync(d_ws, 0, (size_t)(M * 128 * 2 + M) * sizeof(float), stream);
    hipMemsetAsync(out_ring, 0, (size_t)NR * 256 * sizeof(float), stream);

    atom_pool_kernel<<<(N + TA - 1) / TA, 256, 0, stream>>>(
        af, am, Wf, bf, W1, b1, W2, b2, seg, sums,
        (unsigned int*)(sums + (size_t)M * 128), counts, N);
    leaf_kernel<<<(NL + TA - 1) / TA, 256, 0, stream>>>(
        af, am, WL, bL, leaf_idx, out_leaf, NL);
    ring_kernel<<<(NRE + TA - 1) / TA, 256, 0, stream>>>(
        af, am, WR, bR, ring_idx, ring_seg, out_ring, NRE);
    finalize_kernel<<<(M * 128 + 255) / 256, 256, 0, stream>>>(
        sums, maxs, counts, out_mol, M);
}

// Round 2
// 637.558 us; speedup vs baseline: 2.7173x; 2.7173x over previous
//
#include <hip/hip_runtime.h>
#include <math.h>

typedef __attribute__((ext_vector_type(8))) short bf16x8;
typedef __attribute__((ext_vector_type(4))) float f32x4;

__device__ __forceinline__ unsigned short f2bf(float x) {
    unsigned int u = __float_as_uint(x);
    u += 0x7fff + ((u >> 16) & 1);           // round-to-nearest-even
    return (unsigned short)(u >> 16);
}
__device__ __forceinline__ float fast_tanh(float x) {
    float e = __expf(2.0f * x);
    return 1.0f - 2.0f / (e + 1.0f);
}
__device__ __forceinline__ f32x4 mfma16(bf16x8 a, bf16x8 b, f32x4 c) {
    return __builtin_amdgcn_mfma_f32_16x16x32_bf16(a, b, c, 0, 0, 0);
}

// ---------------------------------------------------------------------------
// Prep: fp32 weights -> bf16, transposed [n][kpad] so B-frags are 16B rows
//   WfT [128][64]  (k<39 else 0)
//   W1T [128][384]
//   W2T [128][128]
//   WLT [256][320] (K reordered: k<256 -> orig 39+k (message), 256..294 -> orig
//                   k-256 (features), >=295 -> 0)  -- WRT identical scheme
// ---------------------------------------------------------------------------
__global__ void prep_weights(const float* __restrict__ Wf, const float* __restrict__ W1,
                             const float* __restrict__ W2, const float* __restrict__ WL,
                             const float* __restrict__ WR,
                             unsigned short* __restrict__ WfT, unsigned short* __restrict__ W1T,
                             unsigned short* __restrict__ W2T, unsigned short* __restrict__ WLT,
                             unsigned short* __restrict__ WRT)
{
    int i = blockIdx.x * blockDim.x + threadIdx.x;
    if (i < 8192) {                                   // WfT
        int n = i >> 6, k = i & 63;
        WfT[i] = (k < 39) ? f2bf(Wf[k * 128 + n]) : 0;
    } else if (i < 57344) {                           // W1T
        int j = i - 8192; int n = j / 384, k = j - n * 384;
        W1T[j] = f2bf(W1[k * 128 + n]);
    } else if (i < 73728) {                           // W2T
        int j = i - 57344; int n = j >> 7, k = j & 127;
        W2T[j] = f2bf(W2[k * 128 + n]);
    } else if (i < 155648) {                          // WLT
        int j = i - 73728; int n = j / 320, k = j - n * 320;
        float v;
        if (k < 256)       v = WL[(39 + k) * 256 + n];
        else if (k < 295)  v = WL[(k - 256) * 256 + n];
        else               { WLT[j] = 0; return; }
        WLT[j] = f2bf(v);
    } else if (i < 237568) {                          // WRT
        int j = i - 155648; int n = j / 320, k = j - n * 320;
        float v;
        if (k < 256)       v = WR[(39 + k) * 256 + n];
        else if (k < 295)  v = WR[(k - 256) * 256 + n];
        else               { WRT[j] = 0; return; }
        WRT[j] = f2bf(v);
    }
}

// ---------------------------------------------------------------------------
// Atom chain + pooling. 64 atoms/block, 4 waves in 2x2 (32 rows x 64 cols each)
// ---------------------------------------------------------------------------
__global__ __launch_bounds__(256, 2) void atom_pool_mfma(
    const float* __restrict__ af, const float* __restrict__ am,
    const unsigned short* __restrict__ WfT, const float* __restrict__ bfe,
    const unsigned short* __restrict__ W1T, const float* __restrict__ b1,
    const unsigned short* __restrict__ W2T, const float* __restrict__ b2,
    const int* __restrict__ seg,
    float* __restrict__ out_mol, int* __restrict__ counts, int N)
{
    __shared__ alignas(16) char smem[76800];
    unsigned short (*X1)[72]  = (unsigned short(*)[72])(smem);            // [64][72]
    unsigned short (*X2)[392] = (unsigned short(*)[392])(smem + 9216);    // [64][392]: 0..127=E, 128..383=M
    unsigned short (*Hs)[136] = (unsigned short(*)[136])(smem + 59392);   // [64][136]
    float (*O)[132]           = (float(*)[132])(smem);                    // overlay X1/X2 after phase 3
    __shared__ int sh_seg[64];

    const int t = threadIdx.x;
    const int base = blockIdx.x * 64;

    // ---- stage features (block rows are contiguous in af) ----
    {
        const float* src = af + (size_t)base * 39;
        int limit = (N - base >= 64 ? 64 : N - base) * 39;
        for (int i = t; i < 64 * 39; i += 256) {
            int r = i / 39, k = i - r * 39;
            X1[r][k] = (i < limit) ? f2bf(src[i]) : 0;
        }
        for (int i = t; i < 64 * 33; i += 256) {   // zero K-pad 39..71
            int r = i / 33, k = i - r * 33;
            X1[r][39 + k] = 0;
        }
    }
    // ---- stage message as bf16 into X2 cols 128..383 ----
    {
        const float4* src = (const float4*)(am + (size_t)base * 256);
        int rmax = (N - base >= 64 ? 64 : N - base);
        for (int i = t; i < 64 * 64; i += 256) {
            int r = i >> 6, kq = i & 63;
            float4 v = (r < rmax) ? src[i] : float4{0.f, 0.f, 0.f, 0.f};
            ushort4 u;
            u.x = f2bf(v.x); u.y = f2bf(v.y); u.z = f2bf(v.z); u.w = f2bf(v.w);
            *(ushort4*)&X2[r][128 + kq * 4] = u;
        }
    }
    if (t < 64) sh_seg[t] = (base + t < N) ? seg[base + t] : -1;
    __syncthreads();

    const int lane = t & 63;
    const int w    = t >> 6;
    const int wr   = w >> 1, wc = w & 1;       // wave tile: rows wr*32, cols wc*64
    const int lrow = lane & 15;                // A-row / B-col / D-col
    const int lk   = lane >> 4;                // k-group; D rows = lk*4+r

    // ---- phase 1: E = relu(X1 @ WfT^T + bf), K=64 ----
    {
        f32x4 acc[2][4] = {};
        #pragma unroll
        for (int ks = 0; ks < 2; ++ks) {
            bf16x8 a0 = *(const bf16x8*)&X1[wr * 32 +  0 + lrow][ks * 32 + lk * 8];
            bf16x8 a1 = *(const bf16x8*)&X1[wr * 32 + 16 + lrow][ks * 32 + lk * 8];
            const unsigned short* wb = WfT + (size_t)(wc * 64 + lrow) * 64 + ks * 32 + lk * 8;
            #pragma unroll
            for (int nt = 0; nt < 4; ++nt) {
                bf16x8 b = *(const bf16x8*)(wb + nt * 16 * 64);
                acc[0][nt] = mfma16(a0, b, acc[0][nt]);
                acc[1][nt] = mfma16(a1, b, acc[1][nt]);
            }
        }
        #pragma unroll
        for (int nt = 0; nt < 4; ++nt) {
            int c = wc * 64 + nt * 16 + lrow;
            float bias = bfe[c];
            #pragma unroll
            for (int mt = 0; mt < 2; ++mt) {
                #pragma unroll
                for (int r = 0; r < 4; ++r) {
                    int row = wr * 32 + mt * 16 + lk * 4 + r;
                    X2[row][c] = f2bf(fmaxf(acc[mt][nt][r] + bias, 0.0f));
                }
            }
        }
    }
    __syncthreads();

    // ---- phase 2: H = relu(X2 @ W1T^T + b1), K=384 ----
    {
        f32x4 acc[2][4] = {};
        for (int ks = 0; ks < 12; ++ks) {
            bf16x8 a0 = *(const bf16x8*)&X2[wr * 32 +  0 + lrow][ks * 32 + lk * 8];
            bf16x8 a1 = *(const bf16x8*)&X2[wr * 32 + 16 + lrow][ks * 32 + lk * 8];
            const unsigned short* wb = W1T + (size_t)(wc * 64 + lrow) * 384 + ks * 32 + lk * 8;
            #pragma unroll
            for (int nt = 0; nt < 4; ++nt) {
                bf16x8 b = *(const bf16x8*)(wb + nt * 16 * 384);
                acc[0][nt] = mfma16(a0, b, acc[0][nt]);
                acc[1][nt] = mfma16(a1, b, acc[1][nt]);
            }
        }
        #pragma unroll
        for (int nt = 0; nt < 4; ++nt) {
            int c = wc * 64 + nt * 16 + lrow;
            float bias = b1[c];
            #pragma unroll
            for (int mt = 0; mt < 2; ++mt) {
                #pragma unroll
                for (int r = 0; r < 4; ++r) {
                    int row = wr * 32 + mt * 16 + lk * 4 + r;
                    Hs[row][c] = f2bf(fmaxf(acc[mt][nt][r] + bias, 0.0f));
                }
            }
        }
    }
    __syncthreads();

    // ---- phase 3: Oa = tanh(H @ W2T^T + b2), K=128 ----
    {
        f32x4 acc[2][4] = {};
        #pragma unroll
        for (int ks = 0; ks < 4; ++ks) {
            bf16x8 a0 = *(const bf16x8*)&Hs[wr * 32 +  0 + lrow][ks * 32 + lk * 8];
            bf16x8 a1 = *(const bf16x8*)&Hs[wr * 32 + 16 + lrow][ks * 32 + lk * 8];
            const unsigned short* wb = W2T + (size_t)(wc * 64 + lrow) * 128 + ks * 32 + lk * 8;
            #pragma unroll
            for (int nt = 0; nt < 4; ++nt) {
                bf16x8 b = *(const bf16x8*)(wb + nt * 16 * 128);
                acc[0][nt] = mfma16(a0, b, acc[0][nt]);
                acc[1][nt] = mfma16(a1, b, acc[1][nt]);
            }
        }
        __syncthreads();   // everyone done with X1/X2 (phase-2 inputs) before overlay write
        #pragma unroll
        for (int nt = 0; nt < 4; ++nt) {
            int c = wc * 64 + nt * 16 + lrow;
            float bias = b2[c];
            #pragma unroll
            for (int mt = 0; mt < 2; ++mt) {
                #pragma unroll
                for (int r = 0; r < 4; ++r) {
                    int row = wr * 32 + mt * 16 + lk * 4 + r;
                    O[row][c] = fast_tanh(acc[mt][nt][r] + bias);
                }
            }
        }
    }
    __syncthreads();

    // ---- pooling: sorted segment ids -> run-combined atomics ----
    if (t < 128) {
        const int c = t;
        int cur = -1, runlen = 0;
        float rs = 0.0f, rm = 0.0f;
        for (int a = 0; a < 64; ++a) {
            int m = sh_seg[a];
            if (m < 0) break;
            float v = O[a][c];
            if (m != cur) {
                if (cur >= 0) {
                    atomicAdd(&out_mol[(size_t)cur * 256 + c], rs);
                    atomicMax((unsigned int*)&out_mol[(size_t)cur * 256 + 128 + c],
                              __float_as_uint(rm + 2.0f));
                    if (c == 0) atomicAdd(&counts[cur], runlen);
                }
                cur = m; rs = v; rm = v; runlen = 1;
            } else {
                rs += v; rm = fmaxf(rm, v); ++runlen;
            }
        }
        if (cur >= 0) {
            atomicAdd(&out_mol[(size_t)cur * 256 + c], rs);
            atomicMax((unsigned int*)&out_mol[(size_t)cur * 256 + 128 + c],
                      __float_as_uint(rm + 2.0f));
            if (c == 0) atomicAdd(&counts[cur], runlen);
        }
    }
}

// ---------------------------------------------------------------------------
// Gathered GEMM: X[64][328] (0..255=msg, 256..294=feat, pad 0), 256 out cols.
// RING=0: store tanh rows. RING=1: run-combined segment atomicAdd.
// ---------------------------------------------------------------------------
template <int RING>
__global__ __launch_bounds__(256, 3) void gather_mfma(
    const float* __restrict__ af, const float* __restrict__ am,
    const unsigned short* __restrict__ WT, const float* __restrict__ bias_v,
    const int* __restrict__ idx, const int* __restrict__ rseg,
    float* __restrict__ out, int NROWS)
{
    __shared__ alignas(16) unsigned short X[64][328];
    __shared__ int sh_i[64];
    __shared__ int sh_s[64];

    const int t = threadIdx.x;
    const int base = blockIdx.x * 64;

    if (t < 64) {
        int r = base + t;
        sh_i[t] = (r < NROWS) ? idx[r] : 0;
        sh_s[t] = (RING && r < NROWS) ? rseg[r] : -1;
    }
    __syncthreads();

    // message part -> cols 0..255 (8B-aligned vector writes)
    for (int i = t; i < 64 * 64; i += 256) {
        int r = i >> 6, kq = i & 63;
        float4 v = *(const float4*)(am + ((size_t)sh_i[r] << 8) + kq * 4);
        ushort4 u;
        u.x = f2bf(v.x); u.y = f2bf(v.y); u.z = f2bf(v.z); u.w = f2bf(v.w);
        *(ushort4*)&X[r][kq * 4] = u;
    }
    // feature part -> cols 256..294
    for (int i = t; i < 64 * 39; i += 256) {
        int r = i / 39, k = i - r * 39;
        X[r][256 + k] = f2bf(af[(size_t)sh_i[r] * 39 + k]);
    }
    // zero pad 295..327
    for (int i = t; i < 64 * 33; i += 256) {
        int r = i / 33, k = i - r * 33;
        X[r][295 + k] = 0;
    }
    __syncthreads();

    const int lane = t & 63;
    const int w    = t >> 6;
    const int wr   = w >> 1, wc = w & 1;      // rows wr*32, cols wc*128
    const int lrow = lane & 15;
    const int lk   = lane >> 4;

    f32x4 acc[2][8] = {};
    for (int ks = 0; ks < 10; ++ks) {
        bf16x8 a0 = *(const bf16x8*)&X[wr * 32 +  0 + lrow][ks * 32 + lk * 8];
        bf16x8 a1 = *(const bf16x8*)&X[wr * 32 + 16 + lrow][ks * 32 + lk * 8];
        const unsigned short* wb = WT + (size_t)(wc * 128 + lrow) * 320 + ks * 32 + lk * 8;
        #pragma unroll
        for (int nt = 0; nt < 8; ++nt) {
            bf16x8 b = *(const bf16x8*)(wb + nt * 16 * 320);
            acc[0][nt] = mfma16(a0, b, acc[0][nt]);
            acc[1][nt] = mfma16(a1, b, acc[1][nt]);
        }
    }

    #pragma unroll
    for (int nt = 0; nt < 8; ++nt) {
        int c = wc * 128 + nt * 16 + lrow;
        float bias = bias_v[c];
        #pragma unroll
        for (int mt = 0; mt < 2; ++mt) {
            int r0 = wr * 32 + mt * 16 + lk * 4;
            if (RING) {
                int cur = -1; float accv = 0.0f;
                #pragma unroll
                for (int r = 0; r < 4; ++r) {
                    int s = sh_s[r0 + r];
                    float v = fast_tanh(acc[mt][nt][r] + bias);
                    if (s == cur) accv += v;
                    else {
                        if (cur >= 0) atomicAdd(&out[(size_t)cur * 256 + c], accv);
                        cur = s; accv = v;
                    }
                }
                if (cur >= 0) atomicAdd(&out[(size_t)cur * 256 + c], accv);
            } else {
                #pragma unroll
                for (int r = 0; r < 4; ++r) {
                    int row = base + r0 + r;
                    if (row < NROWS)
                        out[(size_t)row * 256 + c] = fast_tanh(acc[mt][nt][r] + bias);
                }
            }
        }
    }
}

// ---------------------------------------------------------------------------
// Finalize molecule embedding in-place: avg = sum/count, max decode
// ---------------------------------------------------------------------------
__global__ void finalize_kernel(float* __restrict__ out, const int* __restrict__ counts, int M)
{
    int tid = blockIdx.x * blockDim.x + threadIdx.x;
    if (tid >= M * 128) return;
    int m = tid >> 7, c = tid & 127;
    int cnt = counts[m];
    float denom = (cnt > 0) ? (float)cnt : 1.0f;
    float s  = out[(size_t)m * 256 + c];
    float mr = out[(size_t)m * 256 + 128 + c];   // bits(v+2) read as float == v+2
    out[(size_t)m * 256 + c] = s / denom;
    out[(size_t)m * 256 + 128 + c] = (cnt > 0) ? (mr - 2.0f) : 0.0f;
}

extern "C" void kernel_launch(void* const* d_in, const int* in_sizes, int n_in,
                              void* d_out, int out_size, void* d_ws, size_t ws_size,
                              hipStream_t stream) {
    const float* af = (const float*)d_in[0];
    const float* am = (const float*)d_in[1];
    const float* Wf = (const float*)d_in[2];
    const float* bfe = (const float*)d_in[3];
    const float* W1 = (const float*)d_in[4];
    const float* b1 = (const float*)d_in[5];
    const float* W2 = (const float*)d_in[6];
    const float* b2 = (const float*)d_in[7];
    const float* WL = (const float*)d_in[8];
    const float* bL = (const float*)d_in[9];
    const float* WR = (const float*)d_in[10];
    const float* bR = (const float*)d_in[11];
    const int* seg      = (const int*)d_in[12];
    const int* leaf_idx = (const int*)d_in[13];
    const int* ring_idx = (const int*)d_in[14];
    const int* ring_seg = (const int*)d_in[15];

    const int N   = in_sizes[0] / 39;   // 300000
    const int NL  = in_sizes[13];       // 50000
    const int NRE = in_sizes[14];       // 120000
    const int M   = 10000;
    const int NR  = 20000;

    float* out = (float*)d_out;
    float* out_mol  = out;
    float* out_leaf = out + (size_t)M * 256;
    float* out_ring = out + (size_t)M * 256 + (size_t)NL * 256;

    // ws layout
    int* counts = (int*)d_ws;
    unsigned short* WfT = (unsigned short*)((char*)d_ws + 40960);
    unsigned short* W1T = (unsigned short*)((char*)d_ws + 57344);
    unsigned short* W2T = (unsigned short*)((char*)d_ws + 155648);
    unsigned short* WLT = (unsigned short*)((char*)d_ws + 188416);
    unsigned short* WRT = (unsigned short*)((char*)d_ws + 352256);

    hipMemsetAsync(out_mol, 0, (size_t)M * 256 * sizeof(float), stream);
    hipMemsetAsync(out_ring, 0, (size_t)NR * 256 * sizeof(float), stream);
    hipMemsetAsync(counts, 0, (size_t)M * sizeof(int), stream);

    prep_weights<<<(237568 + 255) / 256, 256, 0, stream>>>(
        Wf, W1, W2, WL, WR, WfT, W1T, W2T, WLT, WRT);

    atom_pool_mfma<<<(N + 63) / 64, 256, 0, stream>>>(
        af, am, WfT, bfe, W1T, b1, W2T, b2, seg, out_mol, counts, N);

    gather_mfma<0><<<(NL + 63) / 64, 256, 0, stream>>>(
        af, am, WLT, bL, leaf_idx, (const int*)nullptr, out_leaf, NL);

    gather_mfma<1><<<(NRE + 63) / 64, 256, 0, stream>>>(
        af, am, WRT, bR, ring_idx, ring_seg, out_ring, NRE);

    finalize_kernel<<<(M * 128 + 255) / 256, 256, 0, stream>>>(out_mol, counts, M);
}

// Round 3
// 388.609 us; speedup vs baseline: 4.4580x; 1.6406x over previous
//
#include <hip/hip_runtime.h>
#include <math.h>

typedef __attribute__((ext_vector_type(8))) short bf16x8;
typedef __attribute__((ext_vector_type(4))) float f32x4;

__device__ __forceinline__ unsigned short f2bf(float x) {
    unsigned int u = __float_as_uint(x);
    u += 0x7fff + ((u >> 16) & 1);           // RNE
    return (unsigned short)(u >> 16);
}
__device__ __forceinline__ float bf2f(unsigned short b) {
    return __uint_as_float(((unsigned int)b) << 16);
}
__device__ __forceinline__ float fast_tanh(float x) {
    float e = __expf(2.0f * x);
    return 1.0f - 2.0f / (e + 1.0f);
}
__device__ __forceinline__ f32x4 mfma16(bf16x8 a, bf16x8 b, f32x4 c) {
    return __builtin_amdgcn_mfma_f32_16x16x32_bf16(a, b, c, 0, 0, 0);
}
__device__ __forceinline__ bf16x8 cvt8(float4 u, float4 v) {
    bf16x8 r;
    r[0] = (short)f2bf(u.x); r[1] = (short)f2bf(u.y);
    r[2] = (short)f2bf(u.z); r[3] = (short)f2bf(u.w);
    r[4] = (short)f2bf(v.x); r[5] = (short)f2bf(v.y);
    r[6] = (short)f2bf(v.z); r[7] = (short)f2bf(v.w);
    return r;
}

// ---------------------------------------------------------------------------
// Prep: weights -> frag-major bf16: element((ks*NT+nt)*64+lane, j) =
//   W[k = ks*32+(lane>>4)*8+j][n = nt*16+(lane&15)]  (with per-matrix k-map)
// Slot table (slot = global g>>6):
//   Wf: slots   0..15   (2 ks  x 8 nt),  K=64  (k<39 valid), N=128
//   W1: slots  16..111  (12 ks x 8 nt),  K=384,               N=128
//   W2: slots 112..143  (4 ks  x 8 nt),  K=128,               N=128
//   WL: slots 144..303  (10 ks x 16 nt), K=320 (reordered),   N=256
//   WR: slots 304..463  (10 ks x 16 nt), K=320 (reordered),   N=256
// ---------------------------------------------------------------------------
__global__ void prep_frag(const float* __restrict__ Wf, const float* __restrict__ W1,
                          const float* __restrict__ W2, const float* __restrict__ WL,
                          const float* __restrict__ WR,
                          unsigned short* __restrict__ WfF, unsigned short* __restrict__ W1F,
                          unsigned short* __restrict__ W2F, unsigned short* __restrict__ WLF,
                          unsigned short* __restrict__ WRF)
{
    int g = blockIdx.x * 256 + threadIdx.x;
    if (g >= 29696) return;
    int lane = g & 63, slot = g >> 6;
    int l15 = lane & 15, lkk = lane >> 4;

    unsigned short* dst;
    const float* W;
    int sl, NT, mode;        // mode 0: plain [k][128+n] k<Klim; 1: ring/leaf map [.][256+n]
    int Klim;
    if (slot < 16)       { dst = WfF; W = Wf; sl = slot;       NT = 8;  mode = 0; Klim = 39;  }
    else if (slot < 112) { dst = W1F; W = W1; sl = slot - 16;  NT = 8;  mode = 0; Klim = 384; }
    else if (slot < 144) { dst = W2F; W = W2; sl = slot - 112; NT = 8;  mode = 0; Klim = 128; }
    else if (slot < 304) { dst = WLF; W = WL; sl = slot - 144; NT = 16; mode = 1; Klim = 0;   }
    else                 { dst = WRF; W = WR; sl = slot - 304; NT = 16; mode = 1; Klim = 0;   }

    int ks = sl / NT, nt = sl - ks * NT;
    int n = nt * 16 + l15;
    int kb = ks * 32 + lkk * 8;
    unsigned short* o = dst + ((size_t)sl * 64 + lane) * 8;
    #pragma unroll
    for (int j = 0; j < 8; ++j) {
        int k = kb + j;
        float v;
        if (mode == 0) {
            v = (k < Klim) ? W[(size_t)k * 128 + n] : 0.0f;
        } else {
            if (k < 256)      v = W[(size_t)(39 + k) * 256 + n];
            else if (k < 295) v = W[(size_t)(k - 256) * 256 + n];
            else              v = 0.0f;
        }
        o[j] = f2bf(v);
    }
}

// ---------------------------------------------------------------------------
// Atom chain + pooling. 128 rows/block, 4 waves x 32 rows, NO __syncthreads.
// Per-wave private LDS: E[32][136] bf16, Hs[32][136] bf16; O(bf16) overlays E.
// ---------------------------------------------------------------------------
__global__ __launch_bounds__(256, 2) void atom_pool_v3(
    const float* __restrict__ af, const float* __restrict__ am,
    const unsigned short* __restrict__ WfF, const float* __restrict__ bfe,
    const unsigned short* __restrict__ W1F, const float* __restrict__ b1,
    const unsigned short* __restrict__ W2F, const float* __restrict__ b2,
    const int* __restrict__ seg,
    float* __restrict__ out_mol, int* __restrict__ counts, int N)
{
    __shared__ alignas(16) unsigned short lds[4 * 8704];   // 69632 B
    __shared__ int sseg[4][32];

    const int t = threadIdx.x;
    const int lane = t & 63;
    const int w = t >> 6;
    const int r0 = blockIdx.x * 128 + w * 32;
    const int lrow = lane & 15, lk = lane >> 4;

    unsigned short* E  = lds + w * 8704;
    unsigned short* Hs = E + 4352;
    unsigned short* O  = E;                 // overlay (E dead after phase 2)

    if (lane < 32) {
        int rr = r0 + lane;
        sseg[w][lane] = (rr < N) ? seg[rr] : -1;
    }

    const int rowA0 = min(r0 + lrow, N - 1);
    const int rowA1 = min(r0 + 16 + lrow, N - 1);

    // ---------------- phase 1: E = relu(feat @ Wf + bf), K=64 ----------------
    {
        f32x4 acc[2][8] = {};
        #pragma unroll
        for (int ks = 0; ks < 2; ++ks) {
            bf16x8 a0, a1;
            #pragma unroll
            for (int j = 0; j < 8; ++j) {
                int k = ks * 32 + lk * 8 + j;
                float v0 = (k < 39) ? af[(size_t)rowA0 * 39 + k] : 0.0f;
                float v1 = (k < 39) ? af[(size_t)rowA1 * 39 + k] : 0.0f;
                a0[j] = (short)f2bf(v0); a1[j] = (short)f2bf(v1);
            }
            const bf16x8* B = (const bf16x8*)WfF + ks * 8 * 64 + lane;
            #pragma unroll
            for (int nt = 0; nt < 8; ++nt) {
                bf16x8 b = B[nt * 64];
                acc[0][nt] = mfma16(a0, b, acc[0][nt]);
                acc[1][nt] = mfma16(a1, b, acc[1][nt]);
            }
        }
        #pragma unroll
        for (int nt = 0; nt < 8; ++nt) {
            int c = nt * 16 + lrow;
            float bias = bfe[c];
            #pragma unroll
            for (int mt = 0; mt < 2; ++mt) {
                #pragma unroll
                for (int r = 0; r < 4; ++r) {
                    int row = mt * 16 + lk * 4 + r;
                    E[row * 136 + c] = f2bf(fmaxf(acc[mt][nt][r] + bias, 0.0f));
                }
            }
        }
    }
    asm volatile("s_waitcnt lgkmcnt(0)" ::: "memory");
    __builtin_amdgcn_sched_barrier(0);

    // ------- phase 2: H = relu([E | msg] @ W1 + b1), K = 128 + 256 ----------
    {
        f32x4 acc[2][8] = {};
        #pragma unroll
        for (int ks = 0; ks < 4; ++ks) {
            bf16x8 a0 = *(const bf16x8*)&E[lrow * 136 + ks * 32 + lk * 8];
            bf16x8 a1 = *(const bf16x8*)&E[(16 + lrow) * 136 + ks * 32 + lk * 8];
            const bf16x8* B = (const bf16x8*)W1F + ks * 8 * 64 + lane;
            #pragma unroll
            for (int nt = 0; nt < 8; ++nt) {
                bf16x8 b = B[nt * 64];
                acc[0][nt] = mfma16(a0, b, acc[0][nt]);
                acc[1][nt] = mfma16(a1, b, acc[1][nt]);
            }
        }
        #pragma unroll
        for (int ksg = 0; ksg < 8; ++ksg) {
            int k0 = ksg * 32 + lk * 8;
            const float* p0 = am + ((size_t)rowA0 << 8) + k0;
            const float* p1 = am + ((size_t)rowA1 << 8) + k0;
            bf16x8 a0 = cvt8(*(const float4*)p0, *(const float4*)(p0 + 4));
            bf16x8 a1 = cvt8(*(const float4*)p1, *(const float4*)(p1 + 4));
            const bf16x8* B = (const bf16x8*)W1F + (4 + ksg) * 8 * 64 + lane;
            #pragma unroll
            for (int nt = 0; nt < 8; ++nt) {
                bf16x8 b = B[nt * 64];
                acc[0][nt] = mfma16(a0, b, acc[0][nt]);
                acc[1][nt] = mfma16(a1, b, acc[1][nt]);
            }
        }
        #pragma unroll
        for (int nt = 0; nt < 8; ++nt) {
            int c = nt * 16 + lrow;
            float bias = b1[c];
            #pragma unroll
            for (int mt = 0; mt < 2; ++mt) {
                #pragma unroll
                for (int r = 0; r < 4; ++r) {
                    int row = mt * 16 + lk * 4 + r;
                    Hs[row * 136 + c] = f2bf(fmaxf(acc[mt][nt][r] + bias, 0.0f));
                }
            }
        }
    }
    asm volatile("s_waitcnt lgkmcnt(0)" ::: "memory");
    __builtin_amdgcn_sched_barrier(0);

    // ------------- phase 3: O = tanh(H @ W2 + b2), K=128 --------------------
    {
        f32x4 acc[2][8] = {};
        #pragma unroll
        for (int ks = 0; ks < 4; ++ks) {
            bf16x8 a0 = *(const bf16x8*)&Hs[lrow * 136 + ks * 32 + lk * 8];
            bf16x8 a1 = *(const bf16x8*)&Hs[(16 + lrow) * 136 + ks * 32 + lk * 8];
            const bf16x8* B = (const bf16x8*)W2F + ks * 8 * 64 + lane;
            #pragma unroll
            for (int nt = 0; nt < 8; ++nt) {
                bf16x8 b = B[nt * 64];
                acc[0][nt] = mfma16(a0, b, acc[0][nt]);
                acc[1][nt] = mfma16(a1, b, acc[1][nt]);
            }
        }
        asm volatile("s_waitcnt lgkmcnt(0)" ::: "memory");   // all Hs/E reads done
        __builtin_amdgcn_sched_barrier(0);
        #pragma unroll
        for (int nt = 0; nt < 8; ++nt) {
            int c = nt * 16 + lrow;
            float bias = b2[c];
            #pragma unroll
            for (int mt = 0; mt < 2; ++mt) {
                #pragma unroll
                for (int r = 0; r < 4; ++r) {
                    int row = mt * 16 + lk * 4 + r;
                    O[row * 136 + c] = f2bf(fast_tanh(acc[mt][nt][r] + bias));
                }
            }
        }
    }
    asm volatile("s_waitcnt lgkmcnt(0)" ::: "memory");
    __builtin_amdgcn_sched_barrier(0);

    // -------- pooling: lane handles cols (lane, lane+64) over 32 rows -------
    {
        int cur = -1, runlen = 0;
        float s0 = 0.f, s1 = 0.f, m0 = 0.f, m1 = 0.f;
        #pragma unroll 1
        for (int a = 0; a < 32; ++a) {
            int sg = sseg[w][a];
            if (sg < 0) break;
            float v0 = bf2f(O[a * 136 + lane]);
            float v1 = bf2f(O[a * 136 + 64 + lane]);
            if (sg != cur) {
                if (cur >= 0) {
                    atomicAdd(&out_mol[(size_t)cur * 256 + lane], s0);
                    atomicAdd(&out_mol[(size_t)cur * 256 + 64 + lane], s1);
                    atomicMax((unsigned int*)&out_mol[(size_t)cur * 256 + 128 + lane],
                              __float_as_uint(m0 + 2.0f));
                    atomicMax((unsigned int*)&out_mol[(size_t)cur * 256 + 192 + lane],
                              __float_as_uint(m1 + 2.0f));
                    if (lane == 0) atomicAdd(&counts[cur], runlen);
                }
                cur = sg; s0 = v0; m0 = v0; s1 = v1; m1 = v1; runlen = 1;
            } else {
                s0 += v0; m0 = fmaxf(m0, v0);
                s1 += v1; m1 = fmaxf(m1, v1); ++runlen;
            }
        }
        if (cur >= 0) {
            atomicAdd(&out_mol[(size_t)cur * 256 + lane], s0);
            atomicAdd(&out_mol[(size_t)cur * 256 + 64 + lane], s1);
            atomicMax((unsigned int*)&out_mol[(size_t)cur * 256 + 128 + lane],
                      __float_as_uint(m0 + 2.0f));
            atomicMax((unsigned int*)&out_mol[(size_t)cur * 256 + 192 + lane],
                      __float_as_uint(m1 + 2.0f));
            if (lane == 0) atomicAdd(&counts[cur], runlen);
        }
    }
}

// ---------------------------------------------------------------------------
// Leaf: 64 rows/block, 4 waves x 16 rows, no LDS, gathered A from global.
// ---------------------------------------------------------------------------
__global__ __launch_bounds__(256, 3) void leaf_v3(
    const float* __restrict__ af, const float* __restrict__ am,
    const unsigned short* __restrict__ WF, const float* __restrict__ bv,
    const int* __restrict__ idx, float* __restrict__ out, int NROWS)
{
    const int t = threadIdx.x, lane = t & 63, w = t >> 6;
    const int r0 = blockIdx.x * 64 + w * 16;
    const int lrow = lane & 15, lk = lane >> 4;
    const int ia = idx[min(r0 + lrow, NROWS - 1)];

    f32x4 acc[16] = {};
    #pragma unroll
    for (int ks = 0; ks < 8; ++ks) {
        int k0 = ks * 32 + lk * 8;
        const float* p = am + ((size_t)ia << 8) + k0;
        bf16x8 a = cvt8(*(const float4*)p, *(const float4*)(p + 4));
        const bf16x8* B = (const bf16x8*)WF + ks * 16 * 64 + lane;
        #pragma unroll
        for (int nt = 0; nt < 16; ++nt)
            acc[nt] = mfma16(a, B[nt * 64], acc[nt]);
    }
    #pragma unroll
    for (int ks = 8; ks < 10; ++ks) {
        bf16x8 a;
        #pragma unroll
        for (int j = 0; j < 8; ++j) {
            int k = ks * 32 + lk * 8 + j - 256;
            float v = (k < 39) ? af[(size_t)ia * 39 + k] : 0.0f;
            a[j] = (short)f2bf(v);
        }
        const bf16x8* B = (const bf16x8*)WF + ks * 16 * 64 + lane;
        #pragma unroll
        for (int nt = 0; nt < 16; ++nt)
            acc[nt] = mfma16(a, B[nt * 64], acc[nt]);
    }
    #pragma unroll
    for (int nt = 0; nt < 16; ++nt) {
        int c = nt * 16 + lrow;
        float bias = bv[c];
        #pragma unroll
        for (int r = 0; r < 4; ++r) {
            int row = r0 + lk * 4 + r;
            if (row < NROWS) out[(size_t)row * 256 + c] = fast_tanh(acc[nt][r] + bias);
        }
    }
}

// ---------------------------------------------------------------------------
// Ring: same GEMM, epilogue = run-combined segment atomicAdd (sorted rseg).
// ---------------------------------------------------------------------------
__global__ __launch_bounds__(256, 3) void ring_v3(
    const float* __restrict__ af, const float* __restrict__ am,
    const unsigned short* __restrict__ WF, const float* __restrict__ bv,
    const int* __restrict__ idx, const int* __restrict__ rseg,
    float* __restrict__ out, int NROWS)
{
    const int t = threadIdx.x, lane = t & 63, w = t >> 6;
    const int r0 = blockIdx.x * 64 + w * 16;
    const int lrow = lane & 15, lk = lane >> 4;
    const int ia = idx[min(r0 + lrow, NROWS - 1)];

    f32x4 acc[16] = {};
    #pragma unroll
    for (int ks = 0; ks < 8; ++ks) {
        int k0 = ks * 32 + lk * 8;
        const float* p = am + ((size_t)ia << 8) + k0;
        bf16x8 a = cvt8(*(const float4*)p, *(const float4*)(p + 4));
        const bf16x8* B = (const bf16x8*)WF + ks * 16 * 64 + lane;
        #pragma unroll
        for (int nt = 0; nt < 16; ++nt)
            acc[nt] = mfma16(a, B[nt * 64], acc[nt]);
    }
    #pragma unroll
    for (int ks = 8; ks < 10; ++ks) {
        bf16x8 a;
        #pragma unroll
        for (int j = 0; j < 8; ++j) {
            int k = ks * 32 + lk * 8 + j - 256;
            float v = (k < 39) ? af[(size_t)ia * 39 + k] : 0.0f;
            a[j] = (short)f2bf(v);
        }
        const bf16x8* B = (const bf16x8*)WF + ks * 16 * 64 + lane;
        #pragma unroll
        for (int nt = 0; nt < 16; ++nt)
            acc[nt] = mfma16(a, B[nt * 64], acc[nt]);
    }

    int sg[4];
    #pragma unroll
    for (int r = 0; r < 4; ++r) {
        int rr = r0 + lk * 4 + r;
        sg[r] = (rr < NROWS) ? rseg[rr] : -1;
    }
    #pragma unroll
    for (int nt = 0; nt < 16; ++nt) {
        int c = nt * 16 + lrow;
        float bias = bv[c];
        int cur = -1; float accv = 0.0f;
        #pragma unroll
        for (int r = 0; r < 4; ++r) {
            float v = fast_tanh(acc[nt][r] + bias);
            int s = sg[r];
            if (s != cur) {
                if (cur >= 0) atomicAdd(&out[(size_t)cur * 256 + c], accv);
                cur = s; accv = v;
            } else accv += v;
        }
        if (cur >= 0) atomicAdd(&out[(size_t)cur * 256 + c], accv);
    }
}

// ---------------------------------------------------------------------------
// Finalize molecule embedding in-place: avg = sum/count, max decode
// ---------------------------------------------------------------------------
__global__ void finalize_kernel(float* __restrict__ out, const int* __restrict__ counts, int M)
{
    int tid = blockIdx.x * blockDim.x + threadIdx.x;
    if (tid >= M * 128) return;
    int m = tid >> 7, c = tid & 127;
    int cnt = counts[m];
    float denom = (cnt > 0) ? (float)cnt : 1.0f;
    float s  = out[(size_t)m * 256 + c];
    float mr = out[(size_t)m * 256 + 128 + c];
    out[(size_t)m * 256 + c] = s / denom;
    out[(size_t)m * 256 + 128 + c] = (cnt > 0) ? (mr - 2.0f) : 0.0f;
}

extern "C" void kernel_launch(void* const* d_in, const int* in_sizes, int n_in,
                              void* d_out, int out_size, void* d_ws, size_t ws_size,
                              hipStream_t stream) {
    const float* af = (const float*)d_in[0];
    const float* am = (const float*)d_in[1];
    const float* Wf = (const float*)d_in[2];
    const float* bfe = (const float*)d_in[3];
    const float* W1 = (const float*)d_in[4];
    const float* b1 = (const float*)d_in[5];
    const float* W2 = (const float*)d_in[6];
    const float* b2 = (const float*)d_in[7];
    const float* WL = (const float*)d_in[8];
    const float* bL = (const float*)d_in[9];
    const float* WR = (const float*)d_in[10];
    const float* bR = (const float*)d_in[11];
    const int* seg      = (const int*)d_in[12];
    const int* leaf_idx = (const int*)d_in[13];
    const int* ring_idx = (const int*)d_in[14];
    const int* ring_seg = (const int*)d_in[15];

    const int N   = in_sizes[0] / 39;   // 300000
    const int NL  = in_sizes[13];       // 50000
    const int NRE = in_sizes[14];       // 120000
    const int M   = 10000;
    const int NR  = 20000;

    float* out = (float*)d_out;
    float* out_mol  = out;
    float* out_leaf = out + (size_t)M * 256;
    float* out_ring = out + (size_t)M * 256 + (size_t)NL * 256;

    // ws layout (16B-aligned offsets)
    int* counts = (int*)d_ws;                                       // 40 KB
    unsigned short* WfF = (unsigned short*)((char*)d_ws + 40960);   // 16 KB
    unsigned short* W1F = (unsigned short*)((char*)d_ws + 57344);   // 96 KB
    unsigned short* W2F = (unsigned short*)((char*)d_ws + 155648);  // 32 KB
    unsigned short* WLF = (unsigned short*)((char*)d_ws + 188416);  // 160 KB
    unsigned short* WRF = (unsigned short*)((char*)d_ws + 352256);  // 160 KB

    hipMemsetAsync(out_mol, 0, (size_t)M * 256 * sizeof(float), stream);
    hipMemsetAsync(out_ring, 0, (size_t)NR * 256 * sizeof(float), stream);
    hipMemsetAsync(counts, 0, (size_t)M * sizeof(int), stream);

    prep_frag<<<(29696 + 255) / 256, 256, 0, stream>>>(
        Wf, W1, W2, WL, WR, WfF, W1F, W2F, WLF, WRF);

    atom_pool_v3<<<(N + 127) / 128, 256, 0, stream>>>(
        af, am, WfF, bfe, W1F, b1, W2F, b2, seg, out_mol, counts, N);

    leaf_v3<<<(NL + 63) / 64, 256, 0, stream>>>(
        af, am, WLF, bL, leaf_idx, out_leaf, NL);

    ring_v3<<<(NRE + 63) / 64, 256, 0, stream>>>(
        af, am, WRF, bR, ring_idx, ring_seg, out_ring, NRE);

    finalize_kernel<<<(M * 128 + 255) / 256, 256, 0, stream>>>(out_mol, counts, M);
}

// Round 4
// 371.397 us; speedup vs baseline: 4.6646x; 1.0463x over previous
//
#include <hip/hip_runtime.h>
#include <math.h>

typedef __attribute__((ext_vector_type(8))) short bf16x8;
typedef __attribute__((ext_vector_type(4))) float f32x4;

__device__ __forceinline__ unsigned short f2bf(float x) {
    unsigned int u = __float_as_uint(x);
    u += 0x7fff + ((u >> 16) & 1);           // RNE
    return (unsigned short)(u >> 16);
}
__device__ __forceinline__ float bf2f(unsigned short b) {
    return __uint_as_float(((unsigned int)b) << 16);
}
__device__ __forceinline__ float fast_tanh(float x) {
    float e = __expf(2.0f * x);
    return 1.0f - 2.0f / (e + 1.0f);
}
__device__ __forceinline__ f32x4 mfma16(bf16x8 a, bf16x8 b, f32x4 c) {
    return __builtin_amdgcn_mfma_f32_16x16x32_bf16(a, b, c, 0, 0, 0);
}
__device__ __forceinline__ bf16x8 cvt8(float4 u, float4 v) {
    bf16x8 r;
    r[0] = (short)f2bf(u.x); r[1] = (short)f2bf(u.y);
    r[2] = (short)f2bf(u.z); r[3] = (short)f2bf(u.w);
    r[4] = (short)f2bf(v.x); r[5] = (short)f2bf(v.y);
    r[6] = (short)f2bf(v.z); r[7] = (short)f2bf(v.w);
    return r;
}

// ---------------------------------------------------------------------------
// Prep: weights -> frag-major bf16 (slot = ks*NT+nt; frag row = lane, 8 k each)
// ---------------------------------------------------------------------------
__global__ void prep_frag(const float* __restrict__ Wf, const float* __restrict__ W1,
                          const float* __restrict__ W2, const float* __restrict__ WL,
                          const float* __restrict__ WR,
                          unsigned short* __restrict__ WfF, unsigned short* __restrict__ W1F,
                          unsigned short* __restrict__ W2F, unsigned short* __restrict__ WLF,
                          unsigned short* __restrict__ WRF)
{
    int g = blockIdx.x * 256 + threadIdx.x;
    if (g >= 29696) return;
    int lane = g & 63, slot = g >> 6;
    int l15 = lane & 15, lkk = lane >> 4;

    unsigned short* dst;
    const float* W;
    int sl, NT, mode, Klim;
    if (slot < 16)       { dst = WfF; W = Wf; sl = slot;       NT = 8;  mode = 0; Klim = 39;  }
    else if (slot < 112) { dst = W1F; W = W1; sl = slot - 16;  NT = 8;  mode = 0; Klim = 384; }
    else if (slot < 144) { dst = W2F; W = W2; sl = slot - 112; NT = 8;  mode = 0; Klim = 128; }
    else if (slot < 304) { dst = WLF; W = WL; sl = slot - 144; NT = 16; mode = 1; Klim = 0;   }
    else                 { dst = WRF; W = WR; sl = slot - 304; NT = 16; mode = 1; Klim = 0;   }

    int ks = sl / NT, nt = sl - ks * NT;
    int n = nt * 16 + l15;
    int kb = ks * 32 + lkk * 8;
    unsigned short* o = dst + ((size_t)sl * 64 + lane) * 8;
    #pragma unroll
    for (int j = 0; j < 8; ++j) {
        int k = kb + j;
        float v;
        if (mode == 0) {
            v = (k < Klim) ? W[(size_t)k * 128 + n] : 0.0f;
        } else {
            if (k < 256)      v = W[(size_t)(39 + k) * 256 + n];
            else if (k < 295) v = W[(size_t)(k - 256) * 256 + n];
            else              v = 0.0f;
        }
        o[j] = f2bf(v);
    }
}

// ---------------------------------------------------------------------------
// Atom chain + pooling. 128 rows/block, 4 waves x 32 rows, no block barriers.
// ONE per-wave 8704B LDS buffer overlaid E -> H -> O (lgkmcnt+sched fences).
// 35 KB/block -> 4 blocks/CU -> 16 waves/CU.
// ---------------------------------------------------------------------------
__global__ __launch_bounds__(256, 4) void atom_pool_v4(
    const float* __restrict__ af, const float* __restrict__ am,
    const unsigned short* __restrict__ WfF, const float* __restrict__ bfe,
    const unsigned short* __restrict__ W1F, const float* __restrict__ b1,
    const unsigned short* __restrict__ W2F, const float* __restrict__ b2,
    const int* __restrict__ seg,
    float* __restrict__ out_mol, int* __restrict__ counts, int N)
{
    __shared__ alignas(16) unsigned short lds[4 * 4352];   // 34816 B
    __shared__ int sseg[4][32];

    const int t = threadIdx.x;
    const int lane = t & 63;
    const int w = t >> 6;
    const int r0 = blockIdx.x * 128 + w * 32;
    const int lrow = lane & 15, lk = lane >> 4;

    unsigned short* buf = lds + w * 4352;    // E / H / O overlay

    if (lane < 32) {
        int rr = r0 + lane;
        sseg[w][lane] = (rr < N) ? seg[rr] : -1;
    }

    const int rowA0 = min(r0 + lrow, N - 1);
    const int rowA1 = min(r0 + 16 + lrow, N - 1);

    // ---------------- phase 1: E = relu(feat @ Wf + bf), K=64 ----------------
    {
        f32x4 acc[2][8] = {};
        #pragma unroll
        for (int ks = 0; ks < 2; ++ks) {
            bf16x8 a0, a1;
            #pragma unroll
            for (int j = 0; j < 8; ++j) {
                int k = ks * 32 + lk * 8 + j;
                float v0 = (k < 39) ? af[(size_t)rowA0 * 39 + k] : 0.0f;
                float v1 = (k < 39) ? af[(size_t)rowA1 * 39 + k] : 0.0f;
                a0[j] = (short)f2bf(v0); a1[j] = (short)f2bf(v1);
            }
            const bf16x8* B = (const bf16x8*)WfF + ks * 8 * 64 + lane;
            #pragma unroll
            for (int nt = 0; nt < 8; ++nt) {
                bf16x8 b = B[nt * 64];
                acc[0][nt] = mfma16(a0, b, acc[0][nt]);
                acc[1][nt] = mfma16(a1, b, acc[1][nt]);
            }
        }
        #pragma unroll
        for (int nt = 0; nt < 8; ++nt) {
            int c = nt * 16 + lrow;
            float bias = bfe[c];
            #pragma unroll
            for (int mt = 0; mt < 2; ++mt) {
                #pragma unroll
                for (int r = 0; r < 4; ++r) {
                    int row = mt * 16 + lk * 4 + r;
                    buf[row * 136 + c] = f2bf(fmaxf(acc[mt][nt][r] + bias, 0.0f));
                }
            }
        }
    }
    asm volatile("s_waitcnt lgkmcnt(0)" ::: "memory");
    __builtin_amdgcn_sched_barrier(0);

    // ------- phase 2: H = relu([E | msg] @ W1 + b1), K = 128 + 256 ----------
    {
        f32x4 acc[2][8] = {};
        #pragma unroll
        for (int ks = 0; ks < 4; ++ks) {
            bf16x8 a0 = *(const bf16x8*)&buf[lrow * 136 + ks * 32 + lk * 8];
            bf16x8 a1 = *(const bf16x8*)&buf[(16 + lrow) * 136 + ks * 32 + lk * 8];
            const bf16x8* B = (const bf16x8*)W1F + ks * 8 * 64 + lane;
            #pragma unroll
            for (int nt = 0; nt < 8; ++nt) {
                bf16x8 b = B[nt * 64];
                acc[0][nt] = mfma16(a0, b, acc[0][nt]);
                acc[1][nt] = mfma16(a1, b, acc[1][nt]);
            }
        }
        #pragma unroll
        for (int ksg = 0; ksg < 8; ++ksg) {
            int k0 = ksg * 32 + lk * 8;
            const float* p0 = am + ((size_t)rowA0 << 8) + k0;
            const float* p1 = am + ((size_t)rowA1 << 8) + k0;
            bf16x8 a0 = cvt8(*(const float4*)p0, *(const float4*)(p0 + 4));
            bf16x8 a1 = cvt8(*(const float4*)p1, *(const float4*)(p1 + 4));
            const bf16x8* B = (const bf16x8*)W1F + (4 + ksg) * 8 * 64 + lane;
            #pragma unroll
            for (int nt = 0; nt < 8; ++nt) {
                bf16x8 b = B[nt * 64];
                acc[0][nt] = mfma16(a0, b, acc[0][nt]);
                acc[1][nt] = mfma16(a1, b, acc[1][nt]);
            }
        }
        // all E reads complete before overwriting buf with H
        asm volatile("s_waitcnt lgkmcnt(0)" ::: "memory");
        __builtin_amdgcn_sched_barrier(0);
        #pragma unroll
        for (int nt = 0; nt < 8; ++nt) {
            int c = nt * 16 + lrow;
            float bias = b1[c];
            #pragma unroll
            for (int mt = 0; mt < 2; ++mt) {
                #pragma unroll
                for (int r = 0; r < 4; ++r) {
                    int row = mt * 16 + lk * 4 + r;
                    buf[row * 136 + c] = f2bf(fmaxf(acc[mt][nt][r] + bias, 0.0f));
                }
            }
        }
    }
    asm volatile("s_waitcnt lgkmcnt(0)" ::: "memory");
    __builtin_amdgcn_sched_barrier(0);

    // ------------- phase 3: O = tanh(H @ W2 + b2), K=128 --------------------
    {
        f32x4 acc[2][8] = {};
        #pragma unroll
        for (int ks = 0; ks < 4; ++ks) {
            bf16x8 a0 = *(const bf16x8*)&buf[lrow * 136 + ks * 32 + lk * 8];
            bf16x8 a1 = *(const bf16x8*)&buf[(16 + lrow) * 136 + ks * 32 + lk * 8];
            const bf16x8* B = (const bf16x8*)W2F + ks * 8 * 64 + lane;
            #pragma unroll
            for (int nt = 0; nt < 8; ++nt) {
                bf16x8 b = B[nt * 64];
                acc[0][nt] = mfma16(a0, b, acc[0][nt]);
                acc[1][nt] = mfma16(a1, b, acc[1][nt]);
            }
        }
        asm volatile("s_waitcnt lgkmcnt(0)" ::: "memory");   // all H reads done
        __builtin_amdgcn_sched_barrier(0);
        #pragma unroll
        for (int nt = 0; nt < 8; ++nt) {
            int c = nt * 16 + lrow;
            float bias = b2[c];
            #pragma unroll
            for (int mt = 0; mt < 2; ++mt) {
                #pragma unroll
                for (int r = 0; r < 4; ++r) {
                    int row = mt * 16 + lk * 4 + r;
                    buf[row * 136 + c] = f2bf(fast_tanh(acc[mt][nt][r] + bias));
                }
            }
        }
    }
    asm volatile("s_waitcnt lgkmcnt(0)" ::: "memory");
    __builtin_amdgcn_sched_barrier(0);

    // -------- pooling: lane handles cols (lane, lane+64) over 32 rows -------
    {
        int cur = -1, runlen = 0;
        float s0 = 0.f, s1 = 0.f, m0 = 0.f, m1 = 0.f;
        #pragma unroll 1
        for (int a = 0; a < 32; ++a) {
            int sg = sseg[w][a];
            if (sg < 0) break;
            float v0 = bf2f(buf[a * 136 + lane]);
            float v1 = bf2f(buf[a * 136 + 64 + lane]);
            if (sg != cur) {
                if (cur >= 0) {
                    atomicAdd(&out_mol[(size_t)cur * 256 + lane], s0);
                    atomicAdd(&out_mol[(size_t)cur * 256 + 64 + lane], s1);
                    atomicMax((unsigned int*)&out_mol[(size_t)cur * 256 + 128 + lane],
                              __float_as_uint(m0 + 2.0f));
                    atomicMax((unsigned int*)&out_mol[(size_t)cur * 256 + 192 + lane],
                              __float_as_uint(m1 + 2.0f));
                    if (lane == 0) atomicAdd(&counts[cur], runlen);
                }
                cur = sg; s0 = v0; m0 = v0; s1 = v1; m1 = v1; runlen = 1;
            } else {
                s0 += v0; m0 = fmaxf(m0, v0);
                s1 += v1; m1 = fmaxf(m1, v1); ++runlen;
            }
        }
        if (cur >= 0) {
            atomicAdd(&out_mol[(size_t)cur * 256 + lane], s0);
            atomicAdd(&out_mol[(size_t)cur * 256 + 64 + lane], s1);
            atomicMax((unsigned int*)&out_mol[(size_t)cur * 256 + 128 + lane],
                      __float_as_uint(m0 + 2.0f));
            atomicMax((unsigned int*)&out_mol[(size_t)cur * 256 + 192 + lane],
                      __float_as_uint(m1 + 2.0f));
            if (lane == 0) atomicAdd(&counts[cur], runlen);
        }
    }
}

// ---------------------------------------------------------------------------
// Fused leaf+ring gather-GEMM. Block-uniform branch on blockIdx.
// 64 rows/block; wave (w&1) -> row half (32 rows), (w>>1) -> col half (128).
// B traffic/row is 4x lower than 16-row waves.
// ---------------------------------------------------------------------------
__global__ __launch_bounds__(256, 4) void gather_v4(
    const float* __restrict__ af, const float* __restrict__ am,
    const unsigned short* __restrict__ WLF, const float* __restrict__ bL,
    const unsigned short* __restrict__ WRF, const float* __restrict__ bR,
    const int* __restrict__ leaf_idx, const int* __restrict__ ring_idx,
    const int* __restrict__ rseg,
    float* __restrict__ out_leaf, float* __restrict__ out_ring,
    int NL, int NRE, int nLeafBlocks)
{
    const bool ring = (int)blockIdx.x >= nLeafBlocks;
    const unsigned short* WF = ring ? WRF : WLF;
    const float* bv = ring ? bR : bL;
    const int* idx = ring ? ring_idx : leaf_idx;
    const int NROWS = ring ? NRE : NL;
    const int blk = ring ? (int)blockIdx.x - nLeafBlocks : (int)blockIdx.x;

    const int t = threadIdx.x, lane = t & 63, w = t >> 6;
    const int r0 = blk * 64 + (w & 1) * 32;
    const int colblk = w >> 1;                 // 0/1 -> cols colblk*128
    const int lrow = lane & 15, lk = lane >> 4;
    const int i0 = idx[min(r0 + lrow, NROWS - 1)];
    const int i1 = idx[min(r0 + 16 + lrow, NROWS - 1)];

    f32x4 acc[2][8] = {};
    #pragma unroll
    for (int ks = 0; ks < 8; ++ks) {           // message K-part (256)
        int k0 = ks * 32 + lk * 8;
        const float* p0 = am + ((size_t)i0 << 8) + k0;
        const float* p1 = am + ((size_t)i1 << 8) + k0;
        bf16x8 a0 = cvt8(*(const float4*)p0, *(const float4*)(p0 + 4));
        bf16x8 a1 = cvt8(*(const float4*)p1, *(const float4*)(p1 + 4));
        const bf16x8* B = (const bf16x8*)WF + (ks * 16 + colblk * 8) * 64 + lane;
        #pragma unroll
        for (int nt = 0; nt < 8; ++nt) {
            bf16x8 b = B[nt * 64];
            acc[0][nt] = mfma16(a0, b, acc[0][nt]);
            acc[1][nt] = mfma16(a1, b, acc[1][nt]);
        }
    }
    #pragma unroll
    for (int ks = 8; ks < 10; ++ks) {          // feature K-part (39 + pad)
        bf16x8 a0, a1;
        #pragma unroll
        for (int j = 0; j < 8; ++j) {
            int k = ks * 32 + lk * 8 + j - 256;
            float v0 = (k < 39) ? af[(size_t)i0 * 39 + k] : 0.0f;
            float v1 = (k < 39) ? af[(size_t)i1 * 39 + k] : 0.0f;
            a0[j] = (short)f2bf(v0); a1[j] = (short)f2bf(v1);
        }
        const bf16x8* B = (const bf16x8*)WF + (ks * 16 + colblk * 8) * 64 + lane;
        #pragma unroll
        for (int nt = 0; nt < 8; ++nt) {
            bf16x8 b = B[nt * 64];
            acc[0][nt] = mfma16(a0, b, acc[0][nt]);
            acc[1][nt] = mfma16(a1, b, acc[1][nt]);
        }
    }

    if (!ring) {
        #pragma unroll
        for (int nt = 0; nt < 8; ++nt) {
            int c = colblk * 128 + nt * 16 + lrow;
            float bias = bv[c];
            #pragma unroll
            for (int mt = 0; mt < 2; ++mt) {
                #pragma unroll
                for (int r = 0; r < 4; ++r) {
                    int row = r0 + mt * 16 + lk * 4 + r;
                    if (row < NROWS)
                        out_leaf[(size_t)row * 256 + c] = fast_tanh(acc[mt][nt][r] + bias);
                }
            }
        }
    } else {
        int sg[2][4];
        #pragma unroll
        for (int mt = 0; mt < 2; ++mt)
            #pragma unroll
            for (int r = 0; r < 4; ++r) {
                int rr = r0 + mt * 16 + lk * 4 + r;
                sg[mt][r] = (rr < NROWS) ? rseg[rr] : -1;
            }
        #pragma unroll
        for (int nt = 0; nt < 8; ++nt) {
            int c = colblk * 128 + nt * 16 + lrow;
            float bias = bv[c];
            #pragma unroll
            for (int mt = 0; mt < 2; ++mt) {
                int cur = -1; float accv = 0.0f;
                #pragma unroll
                for (int r = 0; r < 4; ++r) {
                    float v = fast_tanh(acc[mt][nt][r] + bias);
                    int s = sg[mt][r];
                    if (s != cur) {
                        if (cur >= 0) atomicAdd(&out_ring[(size_t)cur * 256 + c], accv);
                        cur = s; accv = v;
                    } else accv += v;
                }
                if (cur >= 0) atomicAdd(&out_ring[(size_t)cur * 256 + c], accv);
            }
        }
    }
}

// ---------------------------------------------------------------------------
// Finalize molecule embedding in-place: avg = sum/count, max decode
// ---------------------------------------------------------------------------
__global__ void finalize_kernel(float* __restrict__ out, const int* __restrict__ counts, int M)
{
    int tid = blockIdx.x * blockDim.x + threadIdx.x;
    if (tid >= M * 128) return;
    int m = tid >> 7, c = tid & 127;
    int cnt = counts[m];
    float denom = (cnt > 0) ? (float)cnt : 1.0f;
    float s  = out[(size_t)m * 256 + c];
    float mr = out[(size_t)m * 256 + 128 + c];
    out[(size_t)m * 256 + c] = s / denom;
    out[(size_t)m * 256 + 128 + c] = (cnt > 0) ? (mr - 2.0f) : 0.0f;
}

extern "C" void kernel_launch(void* const* d_in, const int* in_sizes, int n_in,
                              void* d_out, int out_size, void* d_ws, size_t ws_size,
                              hipStream_t stream) {
    const float* af = (const float*)d_in[0];
    const float* am = (const float*)d_in[1];
    const float* Wf = (const float*)d_in[2];
    const float* bfe = (const float*)d_in[3];
    const float* W1 = (const float*)d_in[4];
    const float* b1 = (const float*)d_in[5];
    const float* W2 = (const float*)d_in[6];
    const float* b2 = (const float*)d_in[7];
    const float* WL = (const float*)d_in[8];
    const float* bL = (const float*)d_in[9];
    const float* WR = (const float*)d_in[10];
    const float* bR = (const float*)d_in[11];
    const int* seg      = (const int*)d_in[12];
    const int* leaf_idx = (const int*)d_in[13];
    const int* ring_idx = (const int*)d_in[14];
    const int* ring_seg = (const int*)d_in[15];

    const int N   = in_sizes[0] / 39;   // 300000
    const int NL  = in_sizes[13];       // 50000
    const int NRE = in_sizes[14];       // 120000
    const int M   = 10000;
    const int NR  = 20000;

    float* out = (float*)d_out;
    float* out_mol  = out;
    float* out_leaf = out + (size_t)M * 256;
    float* out_ring = out + (size_t)M * 256 + (size_t)NL * 256;

    // ws layout (16B-aligned offsets)
    int* counts = (int*)d_ws;                                       // 40 KB
    unsigned short* WfF = (unsigned short*)((char*)d_ws + 40960);   // 16 KB
    unsigned short* W1F = (unsigned short*)((char*)d_ws + 57344);   // 96 KB
    unsigned short* W2F = (unsigned short*)((char*)d_ws + 155648);  // 32 KB
    unsigned short* WLF = (unsigned short*)((char*)d_ws + 188416);  // 160 KB
    unsigned short* WRF = (unsigned short*)((char*)d_ws + 352256);  // 160 KB

    hipMemsetAsync(out_mol, 0, (size_t)M * 256 * sizeof(float), stream);
    hipMemsetAsync(out_ring, 0, (size_t)NR * 256 * sizeof(float), stream);
    hipMemsetAsync(counts, 0, (size_t)M * sizeof(int), stream);

    prep_frag<<<(29696 + 255) / 256, 256, 0, stream>>>(
        Wf, W1, W2, WL, WR, WfF, W1F, W2F, WLF, WRF);

    atom_pool_v4<<<(N + 127) / 128, 256, 0, stream>>>(
        af, am, WfF, bfe, W1F, b1, W2F, b2, seg, out_mol, counts, N);

    const int nLeafBlocks = (NL + 63) / 64;
    const int nRingBlocks = (NRE + 63) / 64;
    gather_v4<<<nLeafBlocks + nRingBlocks, 256, 0, stream>>>(
        af, am, WLF, bL, WRF, bR, leaf_idx, ring_idx, ring_seg,
        out_leaf, out_ring, NL, NRE, nLeafBlocks);

    finalize_kernel<<<(M * 128 + 255) / 256, 256, 0, stream>>>(out_mol, counts, M);
}